// Round 1
// baseline (610.624 us; speedup 1.0000x reference)
//
#include <hip/hip_runtime.h>
#include <hip/hip_bf16.h>
#include <math.h>

#define B_   8
#define N_   1024
#define FIN  128
#define FOUT 128
#define H_   8
#define NEG  0.2f

// ---------------- K1: h_prime[bn][h][f] = sum_i h[bn][i] * W[h][i][f] ----------------
// grid (BN/64, H), block 256
__global__ __launch_bounds__(256) void k_hprime(const float* __restrict__ hsrc,
                                                const float* __restrict__ W,
                                                float* __restrict__ hp) {
    __shared__ float ht[64][32];    // 8 KB
    __shared__ float wt[32][128];   // 16 KB
    const int t  = threadIdx.x;
    const int bn0 = blockIdx.x * 64;
    const int hd  = blockIdx.y;
    const int tx = t & 31, ty = t >> 5;
    const int c0 = tx * 4, r0 = ty * 8;
    float acc[8][4];
#pragma unroll
    for (int k = 0; k < 8; ++k) { acc[k][0]=0.f; acc[k][1]=0.f; acc[k][2]=0.f; acc[k][3]=0.f; }

    for (int k0 = 0; k0 < FIN; k0 += 32) {
#pragma unroll
        for (int q = 0; q < 2; ++q) {           // 512 float4 total, 2 per thread
            int idx = t + q * 256;
            int r = idx >> 3, kq = idx & 7;
            *(float4*)&ht[r][kq * 4] =
                *(const float4*)&hsrc[(size_t)(bn0 + r) * FIN + k0 + kq * 4];
        }
#pragma unroll
        for (int q = 0; q < 4; ++q) {           // 1024 float4 total, 4 per thread
            int idx = t + q * 256;
            int kk = idx >> 5, c4 = idx & 31;
            *(float4*)&wt[kk][c4 * 4] =
                *(const float4*)&W[((size_t)hd * FIN + k0 + kk) * FOUT + c4 * 4];
        }
        __syncthreads();
#pragma unroll 8
        for (int kk = 0; kk < 32; ++kk) {
            float4 wv = *(float4*)&wt[kk][c0];
#pragma unroll
            for (int k = 0; k < 8; ++k) {
                float av = ht[r0 + k][kk];
                acc[k][0] += av * wv.x; acc[k][1] += av * wv.y;
                acc[k][2] += av * wv.z; acc[k][3] += av * wv.w;
            }
        }
        __syncthreads();
    }
#pragma unroll
    for (int k = 0; k < 8; ++k) {
        float4 v = make_float4(acc[k][0], acc[k][1], acc[k][2], acc[k][3]);
        *(float4*)&hp[((size_t)(bn0 + r0 + k) * H_ + hd) * FOUT + c0] = v;
    }
}

// ---------------- K2: s1/s2 per (b,n,h) row ----------------
// grid BN*H/256, block 256
__global__ __launch_bounds__(256) void k_scores(const float* __restrict__ hp,
                                                const float* __restrict__ a,
                                                float* __restrict__ s1,
                                                float* __restrict__ s2) {
    int g = blockIdx.x * 256 + threadIdx.x;   // 0..65535
    const float* row = hp + (size_t)g * FOUT;
    int hd = g & 7;
    const float* a1 = a + (size_t)hd * 2 * FOUT;
    const float* a2 = a1 + FOUT;
    float v1 = 0.f, v2 = 0.f;
#pragma unroll 8
    for (int c = 0; c < FOUT; c += 4) {
        float4 hv  = *(const float4*)&row[c];
        float4 av1 = *(const float4*)&a1[c];
        float4 av2 = *(const float4*)&a2[c];
        v1 += hv.x * av1.x + hv.y * av1.y + hv.z * av1.z + hv.w * av1.w;
        v2 += hv.x * av2.x + hv.y * av2.y + hv.z * av2.z + hv.w * av2.w;
    }
    s1[g] = v1; s2[g] = v2;
}

// ---------------- K3: per (b,i): m[h] = max_j e, zinv[h] = 1/(8*sum_j exp(e-m)) ------
// grid B*N, block 256
__global__ __launch_bounds__(256) void k_mz(const float* __restrict__ s1,
                                            const float* __restrict__ s2,
                                            const int* __restrict__ adj,
                                            const float* __restrict__ bias,
                                            float* __restrict__ m_out,
                                            float* __restrict__ zinv_out) {
    __shared__ float red[256][9];
    const int t = threadIdx.x;
    const int g = blockIdx.x;          // b*N + i
    const int b = g >> 10, i = g & 1023;
    float s1v[8];
#pragma unroll
    for (int hh = 0; hh < 8; ++hh) s1v[hh] = s1[(size_t)g * 8 + hh];

    float tmax[8];
#pragma unroll
    for (int hh = 0; hh < 8; ++hh) tmax[hh] = -1e30f;
    for (int j = t; j < N_; j += 256) {
        if (adj[(size_t)i * N_ + j]) {
            float bv = bias[(size_t)i * N_ + j];
            const float* s2p = s2 + ((size_t)(b << 10) + j) * 8;
#pragma unroll
            for (int hh = 0; hh < 8; ++hh) {
                float x = s1v[hh] + s2p[hh];
                x = (x > 0.f) ? x : NEG * x;
                x += bv;
                tmax[hh] = fmaxf(tmax[hh], x);
            }
        }
    }
#pragma unroll
    for (int hh = 0; hh < 8; ++hh) red[t][hh] = tmax[hh];
    __syncthreads();
    for (int s = 128; s > 0; s >>= 1) {
        if (t < s) {
#pragma unroll
            for (int hh = 0; hh < 8; ++hh)
                red[t][hh] = fmaxf(red[t][hh], red[t + s][hh]);
        }
        __syncthreads();
    }
    float mv[8];
#pragma unroll
    for (int hh = 0; hh < 8; ++hh) mv[hh] = red[0][hh];
    __syncthreads();

    float tsum[8];
#pragma unroll
    for (int hh = 0; hh < 8; ++hh) tsum[hh] = 0.f;
    for (int j = t; j < N_; j += 256) {
        if (adj[(size_t)i * N_ + j]) {
            float bv = bias[(size_t)i * N_ + j];
            const float* s2p = s2 + ((size_t)(b << 10) + j) * 8;
#pragma unroll
            for (int hh = 0; hh < 8; ++hh) {
                float x = s1v[hh] + s2p[hh];
                x = (x > 0.f) ? x : NEG * x;
                x += bv;
                tsum[hh] += __expf(x - mv[hh]);
            }
        }
    }
#pragma unroll
    for (int hh = 0; hh < 8; ++hh) red[t][hh] = tsum[hh];
    __syncthreads();
    for (int s = 128; s > 0; s >>= 1) {
        if (t < s) {
#pragma unroll
            for (int hh = 0; hh < 8; ++hh)
                red[t][hh] += red[t + s][hh];
        }
        __syncthreads();
    }
    if (t < 8) {
        m_out[(size_t)g * 8 + t] = mv[t];
        zinv_out[(size_t)g * 8 + t] = 0.125f / red[0][t];   // folds softmax norm + mean/8
    }
}

// ---------------- K4: out[b][i][f] += sum_j P * hp, P computed on the fly ------------
// grid (N/64, H, B), block 256
__global__ __launch_bounds__(256) void k_pv(const float* __restrict__ hp,
                                            const float* __restrict__ s1,
                                            const float* __restrict__ s2,
                                            const float* __restrict__ m,
                                            const float* __restrict__ zinv,
                                            const int* __restrict__ adj,
                                            const float* __restrict__ bias,
                                            float* __restrict__ out) {
    __shared__ float wl[64][32];     // 8 KB  weights P[i-tile][j-tile]
    __shared__ float hpl[32][128];   // 16 KB h_prime j-tile
    const int t  = threadIdx.x;
    const int tx = t & 31, ty = t >> 5;
    const int c0 = tx * 4, r0 = ty * 8;
    const int i0 = blockIdx.x * 64;
    const int hd = blockIdx.y;
    const int b  = blockIdx.z;
    float acc[8][4];
#pragma unroll
    for (int k = 0; k < 8; ++k) { acc[k][0]=0.f; acc[k][1]=0.f; acc[k][2]=0.f; acc[k][3]=0.f; }

    for (int j0 = 0; j0 < N_; j0 += 32) {
        // stage weights: 64x32 elements, 8 per thread
#pragma unroll
        for (int q = 0; q < 8; ++q) {
            int idx = t + q * 256;
            int r = idx >> 5, jj = idx & 31;
            int i  = i0 + r;
            int gi = (b << 10) + i;
            float wv = 0.f;
            if (adj[(size_t)i * N_ + j0 + jj]) {
                float x = s1[(size_t)gi * 8 + hd] + s2[((size_t)(b << 10) + j0 + jj) * 8 + hd];
                x = (x > 0.f) ? x : NEG * x;
                x += bias[(size_t)i * N_ + j0 + jj];
                wv = __expf(x - m[(size_t)gi * 8 + hd]) * zinv[(size_t)gi * 8 + hd];
            }
            wl[r][jj] = wv;
        }
        // stage h_prime tile: 1024 float4, 4 per thread
#pragma unroll
        for (int q = 0; q < 4; ++q) {
            int f4 = t + q * 256;
            int jj = f4 >> 5, c4 = f4 & 31;
            *(float4*)&hpl[jj][c4 * 4] =
                *(const float4*)&hp[(((size_t)(b << 10) + j0 + jj) * H_ + hd) * FOUT + c4 * 4];
        }
        __syncthreads();
#pragma unroll
        for (int jq = 0; jq < 8; ++jq) {
            float4 hq0 = *(float4*)&hpl[jq * 4 + 0][c0];
            float4 hq1 = *(float4*)&hpl[jq * 4 + 1][c0];
            float4 hq2 = *(float4*)&hpl[jq * 4 + 2][c0];
            float4 hq3 = *(float4*)&hpl[jq * 4 + 3][c0];
#pragma unroll
            for (int k = 0; k < 8; ++k) {
                float4 wv = *(float4*)&wl[r0 + k][jq * 4];
                acc[k][0] += wv.x * hq0.x; acc[k][1] += wv.x * hq0.y;
                acc[k][2] += wv.x * hq0.z; acc[k][3] += wv.x * hq0.w;
                acc[k][0] += wv.y * hq1.x; acc[k][1] += wv.y * hq1.y;
                acc[k][2] += wv.y * hq1.z; acc[k][3] += wv.y * hq1.w;
                acc[k][0] += wv.z * hq2.x; acc[k][1] += wv.z * hq2.y;
                acc[k][2] += wv.z * hq2.z; acc[k][3] += wv.z * hq2.w;
                acc[k][0] += wv.w * hq3.x; acc[k][1] += wv.w * hq3.y;
                acc[k][2] += wv.w * hq3.z; acc[k][3] += wv.w * hq3.w;
            }
        }
        __syncthreads();
    }
#pragma unroll
    for (int k = 0; k < 8; ++k) {
        int i = i0 + r0 + k;
        float* op = out + ((size_t)(b << 10) + i) * FOUT + c0;
        unsafeAtomicAdd(op + 0, acc[k][0]);
        unsafeAtomicAdd(op + 1, acc[k][1]);
        unsafeAtomicAdd(op + 2, acc[k][2]);
        unsafeAtomicAdd(op + 3, acc[k][3]);
    }
}

extern "C" void kernel_launch(void* const* d_in, const int* in_sizes, int n_in,
                              void* d_out, int out_size, void* d_ws, size_t ws_size,
                              hipStream_t stream) {
    const float* hsrc = (const float*)d_in[0];
    const int*   adj  = (const int*)d_in[1];
    const float* bias = (const float*)d_in[2];
    const float* W    = (const float*)d_in[3];
    const float* a    = (const float*)d_in[4];
    float* out = (float*)d_out;

    char* ws = (char*)d_ws;
    float* hp  = (float*)(ws);                       // 8*1024*8*128 f32 = 32 MB
    float* s1  = (float*)(ws + 33554432);            // 64K f32
    float* s2  = s1 + 65536;
    float* mA  = s2 + 65536;
    float* zi  = mA + 65536;

    hipMemsetAsync(d_out, 0, (size_t)out_size * sizeof(float), stream);
    k_hprime<<<dim3(B_ * N_ / 64, H_), 256, 0, stream>>>(hsrc, W, hp);
    k_scores<<<dim3(B_ * N_ * H_ / 256), 256, 0, stream>>>(hp, a, s1, s2);
    k_mz<<<dim3(B_ * N_), 256, 0, stream>>>(s1, s2, adj, bias, mA, zi);
    k_pv<<<dim3(N_ / 64, H_, B_), 256, 0, stream>>>(hp, s1, s2, mA, zi, adj, bias, out);
}

// Round 2
// 215.551 us; speedup vs baseline: 2.8328x; 2.8328x over previous
//
#include <hip/hip_runtime.h>
#include <hip/hip_bf16.h>
#include <math.h>

#define B_   8
#define N_   1024
#define FIN  128
#define FOUT 128
#define H_   8
#define NEG  0.2f

typedef __attribute__((ext_vector_type(4))) float f32x4;
typedef __attribute__((ext_vector_type(8))) short s16x8;

static __device__ __forceinline__ unsigned short f2bf(float f) {
    unsigned int u = __float_as_uint(f);
    unsigned int r = (u + 0x7fffu + ((u >> 16) & 1u)) >> 16;   // RNE
    return (unsigned short)r;
}

// ---------------- K1: h' GEMM + transpose-to-bf16 + s1/s2 epilogue ----------------
// grid (BN/64, H), block 256
union SmemK1 {
    struct { float ht[64][32]; float wt[32][128]; } s;   // 24 KB
    float tr[64][129];                                    // 33 KB (padded transpose buf)
};

__global__ __launch_bounds__(256) void k_hprime(const float* __restrict__ hsrc,
                                                const float* __restrict__ W,
                                                const float* __restrict__ a,
                                                unsigned short* __restrict__ hpT,
                                                float* __restrict__ s1,
                                                float* __restrict__ s2T) {
    __shared__ SmemK1 sm;
    const int t   = threadIdx.x;
    const int bn0 = blockIdx.x * 64;
    const int hd  = blockIdx.y;
    const int tx = t & 31, ty = t >> 5;
    const int c0 = tx * 4, r0 = ty * 8;
    float acc[8][4];
#pragma unroll
    for (int k = 0; k < 8; ++k) { acc[k][0]=0.f; acc[k][1]=0.f; acc[k][2]=0.f; acc[k][3]=0.f; }

    for (int k0 = 0; k0 < FIN; k0 += 32) {
#pragma unroll
        for (int q = 0; q < 2; ++q) {
            int idx = t + q * 256;
            int r = idx >> 3, kq = idx & 7;
            *(float4*)&sm.s.ht[r][kq * 4] =
                *(const float4*)&hsrc[(size_t)(bn0 + r) * FIN + k0 + kq * 4];
        }
#pragma unroll
        for (int q = 0; q < 4; ++q) {
            int idx = t + q * 256;
            int kk = idx >> 5, c4 = idx & 31;
            *(float4*)&sm.s.wt[kk][c4 * 4] =
                *(const float4*)&W[((size_t)hd * FIN + k0 + kk) * FOUT + c4 * 4];
        }
        __syncthreads();
#pragma unroll 8
        for (int kk = 0; kk < 32; ++kk) {
            float4 wv = *(float4*)&sm.s.wt[kk][c0];
#pragma unroll
            for (int k = 0; k < 8; ++k) {
                float av = sm.s.ht[r0 + k][kk];
                acc[k][0] += av * wv.x; acc[k][1] += av * wv.y;
                acc[k][2] += av * wv.z; acc[k][3] += av * wv.w;
            }
        }
        __syncthreads();
    }
    // stage f32 result into padded transpose buffer
#pragma unroll
    for (int k = 0; k < 8; ++k) {
        sm.tr[r0 + k][c0 + 0] = acc[k][0];
        sm.tr[r0 + k][c0 + 1] = acc[k][1];
        sm.tr[r0 + k][c0 + 2] = acc[k][2];
        sm.tr[r0 + k][c0 + 3] = acc[k][3];
    }
    __syncthreads();

    // transposed bf16 write: thread t handles f = t>>1, n-segment (t&1)*32..+31
    {
        const int f   = t >> 1;
        const int seg = (t & 1) * 32;
        const int b   = bn0 >> 10;
        const int n0  = bn0 & 1023;
        unsigned short* dst = hpT + (((size_t)(b * H_ + hd) * FOUT + f) * N_) + n0 + seg;
#pragma unroll
        for (int c = 0; c < 4; ++c) {
            s16x8 v;
#pragma unroll
            for (int u = 0; u < 8; ++u)
                v[u] = (short)f2bf(sm.tr[seg + c * 8 + u][f]);
            *(s16x8*)(dst + c * 8) = v;
        }
    }
    // s1/s2 from exact f32 h' (threads 0..63)
    if (t < 64) {
        const float* a1 = a + (size_t)hd * 2 * FOUT;
        const float* a2 = a1 + FOUT;
        float v1 = 0.f, v2 = 0.f;
#pragma unroll 16
        for (int f = 0; f < FOUT; ++f) {
            float hv = sm.tr[t][f];
            v1 += hv * a1[f];
            v2 += hv * a2[f];
        }
        int bn = bn0 + t;
        s1[(size_t)bn * 8 + hd]        = v1;
        s2T[(size_t)hd * (B_ * N_) + bn] = v2;
    }
}

// ---------------- K2: fused P-gen + MFMA PV + online Z + atomic out ----------------
// grid (N/64, H, B), block 256 (4 waves, each 32 rows x 64 cols)
__global__ __launch_bounds__(256) void k_pv2(const unsigned short* __restrict__ hpT,
                                             const float* __restrict__ s1,
                                             const float* __restrict__ s2T,
                                             const int* __restrict__ adj,
                                             const float* __restrict__ bias,
                                             float* __restrict__ out) {
    __shared__ __align__(16) unsigned short P[64][72];   // 9 KB, padded stride
    __shared__ float Zl[64];
    const int t    = threadIdx.x;
    const int lane = t & 63;
    const int wave = t >> 6;
    const int i0 = blockIdx.x * 64;
    const int hd = blockIdx.y;
    const int b  = blockIdx.z;

    // P-gen assignment: one row per 4 threads, 16 consecutive j each
    const int prow = t >> 2;
    const int pj0  = (t & 3) * 16;
    const int gi   = (b << 10) + i0 + prow;
    const float s1v = s1[(size_t)gi * 8 + hd];
    const int*   adj_row  = adj  + (size_t)(i0 + prow) * N_;
    const float* bias_row = bias + (size_t)(i0 + prow) * N_;
    const float* s2p      = s2T + (size_t)hd * (B_ * N_) + (b << 10);

    // wave output tile
    const int wr = (wave & 1) * 32;
    const int wc = (wave >> 1) * 64;
    const int arow0 = wr + (lane & 15);
    const int koff  = (lane >> 4) * 8;

    const unsigned short* bbase =
        hpT + ((size_t)(b * H_ + hd) * FOUT + wc + (lane & 15)) * N_ + koff;

    f32x4 acc[2][4];
#pragma unroll
    for (int i = 0; i < 2; ++i)
#pragma unroll
        for (int j = 0; j < 4; ++j) acc[i][j] = (f32x4){0.f, 0.f, 0.f, 0.f};

    float z_acc = 0.f;

    for (int j0 = 0; j0 < N_; j0 += 64) {
        __syncthreads();   // previous MFMA phase done reading P
        // ---- build P tile (64 x 64) + accumulate Z
#pragma unroll
        for (int q = 0; q < 4; ++q) {
            const int jb = j0 + pj0 + q * 4;
            int4   av = *(const int4*)  &adj_row[jb];
            float4 bv = *(const float4*)&bias_row[jb];
            float4 sv = *(const float4*)&s2p[jb];
            float x0 = s1v + sv.x; x0 = (x0 > 0.f ? x0 : NEG * x0) + bv.x;
            float x1 = s1v + sv.y; x1 = (x1 > 0.f ? x1 : NEG * x1) + bv.y;
            float x2 = s1v + sv.z; x2 = (x2 > 0.f ? x2 : NEG * x2) + bv.z;
            float x3 = s1v + sv.w; x3 = (x3 > 0.f ? x3 : NEG * x3) + bv.w;
            float p0 = av.x ? __expf(x0) : 0.f;
            float p1 = av.y ? __expf(x1) : 0.f;
            float p2 = av.z ? __expf(x2) : 0.f;
            float p3 = av.w ? __expf(x3) : 0.f;
            z_acc += (p0 + p1) + (p2 + p3);
            ushort4 pk = make_ushort4(f2bf(p0), f2bf(p1), f2bf(p2), f2bf(p3));
            *(ushort4*)&P[prow][pj0 + q * 4] = pk;
        }
        __syncthreads();
        // ---- MFMA phase: A from LDS, B from global (L2-resident)
#pragma unroll
        for (int kw = 0; kw < 2; ++kw) {
            s16x8 a0 = *(const s16x8*)&P[arow0][kw * 32 + koff];
            s16x8 a1 = *(const s16x8*)&P[arow0 + 16][kw * 32 + koff];
            const unsigned short* bp = bbase + j0 + kw * 32;
#pragma unroll
            for (int fc = 0; fc < 4; ++fc) {
                s16x8 bf = *(const s16x8*)(bp + (size_t)fc * 16 * N_);
                acc[0][fc] = __builtin_amdgcn_mfma_f32_16x16x32_bf16(a0, bf, acc[0][fc], 0, 0, 0);
                acc[1][fc] = __builtin_amdgcn_mfma_f32_16x16x32_bf16(a1, bf, acc[1][fc], 0, 0, 0);
            }
        }
    }

    // Z: reduce 4 lanes per row (lanes grouped consecutively)
    float z2 = z_acc + __shfl_xor(z_acc, 1);
    float z4 = z2 + __shfl_xor(z2, 2);
    if ((lane & 3) == 0) Zl[prow] = 0.125f / z4;   // folds softmax norm + head-mean
    __syncthreads();

    // epilogue: C/D layout col=lane&15, row=(lane>>4)*4+reg
#pragma unroll
    for (int fr = 0; fr < 2; ++fr) {
#pragma unroll
        for (int r = 0; r < 4; ++r) {
            const int il = wr + fr * 16 + (lane >> 4) * 4 + r;
            const float sc = Zl[il];
            float* op = out + ((size_t)((b << 10) + i0 + il)) * FOUT + wc + (lane & 15);
#pragma unroll
            for (int fc = 0; fc < 4; ++fc)
                unsafeAtomicAdd(op + fc * 16, acc[fr][fc][r] * sc);
        }
    }
}

extern "C" void kernel_launch(void* const* d_in, const int* in_sizes, int n_in,
                              void* d_out, int out_size, void* d_ws, size_t ws_size,
                              hipStream_t stream) {
    const float* hsrc = (const float*)d_in[0];
    const int*   adj  = (const int*)d_in[1];
    const float* bias = (const float*)d_in[2];
    const float* W    = (const float*)d_in[3];
    const float* a    = (const float*)d_in[4];
    float* out = (float*)d_out;

    char* ws = (char*)d_ws;
    unsigned short* hpT = (unsigned short*)ws;                 // 8*8*128*1024 bf16 = 16 MB
    float* s1  = (float*)(ws + 16777216);                      // 64K f32 = 256 KB
    float* s2T = s1 + 65536;                                   // 256 KB

    hipMemsetAsync(d_out, 0, (size_t)out_size * sizeof(float), stream);
    k_hprime<<<dim3(B_ * N_ / 64, H_), 256, 0, stream>>>(hsrc, W, a, hpT, s1, s2T);
    k_pv2<<<dim3(N_ / 64, H_, B_), 256, 0, stream>>>(hpT, s1, s2T, adj, bias, out);
}

// Round 3
// 204.030 us; speedup vs baseline: 2.9928x; 1.0565x over previous
//
#include <hip/hip_runtime.h>
#include <hip/hip_bf16.h>
#include <math.h>

#define B_   8
#define N_   1024
#define FIN  128
#define FOUT 128
#define H_   8
#define NEG  0.2f

typedef __attribute__((ext_vector_type(4))) float f32x4;
typedef __attribute__((ext_vector_type(8))) short s16x8;

static __device__ __forceinline__ unsigned short f2bf(float f) {
    unsigned int u = __float_as_uint(f);
    unsigned int r = (u + 0x7fffu + ((u >> 16) & 1u)) >> 16;   // RNE
    return (unsigned short)r;
}

// ---------------- K0: pack adj into bitmask (1024x1024 bits = 128 KB) ----------------
__global__ __launch_bounds__(256) void k_pack(const int* __restrict__ adj,
                                              unsigned int* __restrict__ bits) {
    int base = blockIdx.x * 256 + threadIdx.x;
    unsigned long long m = __ballot(adj[base] != 0);
    int lane = threadIdx.x & 63;
    if (lane == 0) {
        int widx = base >> 5;
        bits[widx]     = (unsigned int)m;
        bits[widx + 1] = (unsigned int)(m >> 32);
    }
}

// ---------------- K1: h' GEMM + transpose-to-bf16 + s1/s2 epilogue ----------------
// grid (BN/64, H), block 256
union SmemK1 {
    struct { float ht[64][32]; float wt[32][128]; } s;   // 24 KB
    float tr[64][129];                                    // 33 KB (padded transpose buf)
};

__global__ __launch_bounds__(256) void k_hprime(const float* __restrict__ hsrc,
                                                const float* __restrict__ W,
                                                const float* __restrict__ a,
                                                unsigned short* __restrict__ hpT,
                                                float* __restrict__ s1,
                                                float* __restrict__ s2T) {
    __shared__ SmemK1 sm;
    const int t   = threadIdx.x;
    const int bn0 = blockIdx.x * 64;
    const int hd  = blockIdx.y;
    const int tx = t & 31, ty = t >> 5;
    const int c0 = tx * 4, r0 = ty * 8;
    float acc[8][4];
#pragma unroll
    for (int k = 0; k < 8; ++k) { acc[k][0]=0.f; acc[k][1]=0.f; acc[k][2]=0.f; acc[k][3]=0.f; }

    for (int k0 = 0; k0 < FIN; k0 += 32) {
#pragma unroll
        for (int q = 0; q < 2; ++q) {
            int idx = t + q * 256;
            int r = idx >> 3, kq = idx & 7;
            *(float4*)&sm.s.ht[r][kq * 4] =
                *(const float4*)&hsrc[(size_t)(bn0 + r) * FIN + k0 + kq * 4];
        }
#pragma unroll
        for (int q = 0; q < 4; ++q) {
            int idx = t + q * 256;
            int kk = idx >> 5, c4 = idx & 31;
            *(float4*)&sm.s.wt[kk][c4 * 4] =
                *(const float4*)&W[((size_t)hd * FIN + k0 + kk) * FOUT + c4 * 4];
        }
        __syncthreads();
#pragma unroll 8
        for (int kk = 0; kk < 32; ++kk) {
            float4 wv = *(float4*)&sm.s.wt[kk][c0];
#pragma unroll
            for (int k = 0; k < 8; ++k) {
                float av = sm.s.ht[r0 + k][kk];
                acc[k][0] += av * wv.x; acc[k][1] += av * wv.y;
                acc[k][2] += av * wv.z; acc[k][3] += av * wv.w;
            }
        }
        __syncthreads();
    }
    // stage f32 result into padded transpose buffer
#pragma unroll
    for (int k = 0; k < 8; ++k) {
        sm.tr[r0 + k][c0 + 0] = acc[k][0];
        sm.tr[r0 + k][c0 + 1] = acc[k][1];
        sm.tr[r0 + k][c0 + 2] = acc[k][2];
        sm.tr[r0 + k][c0 + 3] = acc[k][3];
    }
    __syncthreads();

    // transposed bf16 write: thread t handles f = t>>1, n-segment (t&1)*32..+31
    {
        const int f   = t >> 1;
        const int seg = (t & 1) * 32;
        const int b   = bn0 >> 10;
        const int n0  = bn0 & 1023;
        unsigned short* dst = hpT + (((size_t)(b * H_ + hd) * FOUT + f) * N_) + n0 + seg;
#pragma unroll
        for (int c = 0; c < 4; ++c) {
            s16x8 v;
#pragma unroll
            for (int u = 0; u < 8; ++u)
                v[u] = (short)f2bf(sm.tr[seg + c * 8 + u][f]);
            *(s16x8*)(dst + c * 8) = v;
        }
    }
    // s1/s2 from exact f32 h': 4 threads per row, 32 f each, shfl reduce
    {
        const int row = t >> 2, f0 = (t & 3) * 32;
        const float* a1 = a + (size_t)hd * 2 * FOUT;
        const float* a2 = a1 + FOUT;
        float v1 = 0.f, v2 = 0.f;
#pragma unroll 8
        for (int fi = 0; fi < 32; ++fi) {
            float hv = sm.tr[row][f0 + fi];
            v1 += hv * a1[f0 + fi];
            v2 += hv * a2[f0 + fi];
        }
        v1 += __shfl_xor(v1, 1); v1 += __shfl_xor(v1, 2);
        v2 += __shfl_xor(v2, 1); v2 += __shfl_xor(v2, 2);
        if ((t & 3) == 0) {
            int bn = bn0 + row;
            s1[(size_t)bn * 8 + hd]          = v1;
            s2T[(size_t)hd * (B_ * N_) + bn] = v2;
        }
    }
}

// ---------------- K2: fused P-gen + MFMA PV, single-barrier pipelined ----------------
// grid (N/64, H, B), block 256 (4 waves, each 32 rows x 64 cols)
__global__ __launch_bounds__(256) void k_pv2(const unsigned short* __restrict__ hpT,
                                             const float* __restrict__ s1,
                                             const float* __restrict__ s2T,
                                             const unsigned int* __restrict__ adjbits,
                                             const float* __restrict__ bias,
                                             float* __restrict__ out) {
    __shared__ __align__(16) unsigned short P[2][64][72];   // 18 KB double-buffered
    __shared__ float Zl[64];
    const int t    = threadIdx.x;
    const int lane = t & 63;
    const int wave = t >> 6;
    const int i0 = blockIdx.x * 64;
    const int hd = blockIdx.y;
    const int b  = blockIdx.z;

    // P-gen assignment: one row per 4 threads, 16 consecutive j each
    const int prow = t >> 2;
    const int pj0  = (t & 3) * 16;
    const int gi   = (b << 10) + i0 + prow;
    const float s1v = s1[(size_t)gi * 8 + hd];
    const unsigned int* abr = adjbits + (size_t)(i0 + prow) * 32;
    const float* bias_row   = bias + (size_t)(i0 + prow) * N_;
    const float* s2p        = s2T + (size_t)hd * (B_ * N_) + (b << 10);

    // wave output tile
    const int wr = (wave & 1) * 32;
    const int wc = (wave >> 1) * 64;
    const int arow0 = wr + (lane & 15);
    const int koff  = (lane >> 4) * 8;
    const unsigned short* bbase =
        hpT + ((size_t)(b * H_ + hd) * FOUT + wc + (lane & 15)) * N_ + koff;

    f32x4 acc[2][4];
#pragma unroll
    for (int i = 0; i < 2; ++i)
#pragma unroll
        for (int j = 0; j < 4; ++j) acc[i][j] = (f32x4){0.f, 0.f, 0.f, 0.f};
    float z_acc = 0.f;

    auto load_it = [&](int j0, unsigned int& aw_, float4 (&bv_)[4], float4 (&sv_)[4]) {
        aw_ = (abr[(j0 + pj0) >> 5] >> (pj0 & 16)) & 0xffffu;
#pragma unroll
        for (int q = 0; q < 4; ++q) {
            bv_[q] = *(const float4*)&bias_row[j0 + pj0 + q * 4];
            sv_[q] = *(const float4*)&s2p[j0 + pj0 + q * 4];
        }
    };
    auto comp_store = [&](int buf, unsigned int aw_, float4 (&bv_)[4], float4 (&sv_)[4]) {
#pragma unroll
        for (int q = 0; q < 4; ++q) {
            float x0 = s1v + sv_[q].x; x0 = (x0 > 0.f ? x0 : NEG * x0) + bv_[q].x;
            float x1 = s1v + sv_[q].y; x1 = (x1 > 0.f ? x1 : NEG * x1) + bv_[q].y;
            float x2 = s1v + sv_[q].z; x2 = (x2 > 0.f ? x2 : NEG * x2) + bv_[q].z;
            float x3 = s1v + sv_[q].w; x3 = (x3 > 0.f ? x3 : NEG * x3) + bv_[q].w;
            float p0 = (aw_ >> (q * 4 + 0)) & 1 ? __expf(x0) : 0.f;
            float p1 = (aw_ >> (q * 4 + 1)) & 1 ? __expf(x1) : 0.f;
            float p2 = (aw_ >> (q * 4 + 2)) & 1 ? __expf(x2) : 0.f;
            float p3 = (aw_ >> (q * 4 + 3)) & 1 ? __expf(x3) : 0.f;
            z_acc += (p0 + p1) + (p2 + p3);
            *(ushort4*)&P[buf][prow][pj0 + q * 4] =
                make_ushort4(f2bf(p0), f2bf(p1), f2bf(p2), f2bf(p3));
        }
    };

    // prologue: build P[0]
    {
        unsigned int aw; float4 bv[4], sv[4];
        load_it(0, aw, bv, sv);
        comp_store(0, aw, bv, sv);
    }
    __syncthreads();

    for (int it = 0; it < 16; ++it) {
        const int cur = it & 1;
        const int j0  = it * 64;
        unsigned int naw; float4 nbv[4], nsv[4];
        if (it < 15) load_it(j0 + 64, naw, nbv, nsv);   // loads overlap MFMA below
        // ---- MFMA phase on P[cur]: A from LDS, B from global (L2-resident)
#pragma unroll
        for (int kw = 0; kw < 2; ++kw) {
            s16x8 a0 = *(const s16x8*)&P[cur][arow0][kw * 32 + koff];
            s16x8 a1 = *(const s16x8*)&P[cur][arow0 + 16][kw * 32 + koff];
            const unsigned short* bp = bbase + j0 + kw * 32;
#pragma unroll
            for (int fc = 0; fc < 4; ++fc) {
                s16x8 bf = *(const s16x8*)(bp + (size_t)fc * 16 * N_);
                acc[0][fc] = __builtin_amdgcn_mfma_f32_16x16x32_bf16(a0, bf, acc[0][fc], 0, 0, 0);
                acc[1][fc] = __builtin_amdgcn_mfma_f32_16x16x32_bf16(a1, bf, acc[1][fc], 0, 0, 0);
            }
        }
        // ---- build next P tile while MFMAs drain
        if (it < 15) comp_store(cur ^ 1, naw, nbv, nsv);
        __syncthreads();
    }

    // Z: reduce 4 lanes per row (lanes grouped consecutively)
    float z2 = z_acc + __shfl_xor(z_acc, 1);
    float z4 = z2 + __shfl_xor(z2, 2);
    if ((lane & 3) == 0) Zl[prow] = 0.125f / z4;   // folds softmax norm + head-mean
    __syncthreads();

    // epilogue: C/D layout col=lane&15, row=(lane>>4)*4+reg
#pragma unroll
    for (int fr = 0; fr < 2; ++fr) {
#pragma unroll
        for (int r = 0; r < 4; ++r) {
            const int il = wr + fr * 16 + (lane >> 4) * 4 + r;
            const float sc = Zl[il];
            float* op = out + ((size_t)((b << 10) + i0 + il)) * FOUT + wc + (lane & 15);
#pragma unroll
            for (int fc = 0; fc < 4; ++fc)
                unsafeAtomicAdd(op + fc * 16, acc[fr][fc][r] * sc);
        }
    }
}

extern "C" void kernel_launch(void* const* d_in, const int* in_sizes, int n_in,
                              void* d_out, int out_size, void* d_ws, size_t ws_size,
                              hipStream_t stream) {
    const float* hsrc = (const float*)d_in[0];
    const int*   adj  = (const int*)d_in[1];
    const float* bias = (const float*)d_in[2];
    const float* W    = (const float*)d_in[3];
    const float* a    = (const float*)d_in[4];
    float* out = (float*)d_out;

    char* ws = (char*)d_ws;
    unsigned short* hpT = (unsigned short*)ws;                 // 8*8*128*1024 bf16 = 16 MB
    float* s1  = (float*)(ws + 16777216);                      // 64K f32 = 256 KB
    float* s2T = s1 + 65536;                                   // 256 KB
    unsigned int* adjbits = (unsigned int*)(s2T + 65536);      // 128 KB

    hipMemsetAsync(d_out, 0, (size_t)out_size * sizeof(float), stream);
    k_pack<<<dim3(N_ * N_ / 256), 256, 0, stream>>>(adj, adjbits);
    k_hprime<<<dim3(B_ * N_ / 64, H_), 256, 0, stream>>>(hsrc, W, a, hpT, s1, s2T);
    k_pv2<<<dim3(N_ / 64, H_, B_), 256, 0, stream>>>(hpT, s1, s2T, adjbits, bias, out);
}